// Round 14
// baseline (253.475 us; speedup 1.0000x reference)
//
#include <hip/hip_runtime.h>
#include <hip/hip_bf16.h>

#define SEQ 4096
#define BATCH 2
#define HEADS 16
#define DHEAD 64
#define HID 1024

typedef unsigned short ushort_t;
typedef unsigned int uint_t;
typedef __attribute__((ext_vector_type(8))) short short8;
typedef __attribute__((ext_vector_type(4))) float f32x4;
typedef __attribute__((ext_vector_type(16))) float f32x16;
typedef __attribute__((ext_vector_type(4))) uint_t u32x4;

__device__ __forceinline__ float exp2_fast(float x) {
  return __builtin_amdgcn_exp2f(x);
}

__device__ __forceinline__ float max3f(float a, float b, float c) {
  float r;
  asm("v_max3_f32 %0, %1, %2, %3" : "=v"(r) : "v"(a), "v"(b), "v"(c));
  return r;
}

__device__ __forceinline__ ushort_t f2b(float f) {
  unsigned u = __builtin_bit_cast(unsigned, f);
  unsigned r = 0x7fffu + ((u >> 16) & 1u);
  return (ushort_t)((u + r) >> 16);
}

__device__ __forceinline__ uint_t cvt_pk_bf16(float lo, float hi) {
  uint_t r;
  asm("v_cvt_pk_bf16_f32 %0, %1, %2" : "=v"(r) : "v"(lo), "v"(hi));
  return r;
}

__device__ __forceinline__ void permlane_swap(uint_t& a, uint_t& b) {
  asm("v_permlane32_swap_b32 %0, %1" : "+v"(a), "+v"(b));
}

__device__ __forceinline__ void gload16(const void* g, void* l) {
  __builtin_amdgcn_global_load_lds((const __attribute__((address_space(1))) void*)g,
                                   (__attribute__((address_space(3))) void*)l, 16, 0, 0);
}

__device__ __forceinline__ f32x4 mfma_bf16(short8 a, short8 b, f32x4 c) {
  return __builtin_amdgcn_mfma_f32_16x16x32_bf16(a, b, c, 0, 0, 0);
}

__device__ __forceinline__ f32x16 mfma32_bf16(short8 a, short8 b, f32x16 c) {
  return __builtin_amdgcn_mfma_f32_32x32x16_bf16(a, b, c, 0, 0, 0);
}

// ---------------- fp32 -> bf16 elementwise (vectorized) ----------------
__global__ void cvt_kernel(const float* __restrict__ in, ushort_t* __restrict__ out, int n4) {
  int i = blockIdx.x * blockDim.x + threadIdx.x;
  if (i >= n4) return;
  float4 v = reinterpret_cast<const float4*>(in)[i];
  ushort4 o;
  o.x = f2b(v.x); o.y = f2b(v.y); o.z = f2b(v.z); o.w = f2b(v.w);
  reinterpret_cast<ushort4*>(out)[i] = o;
}

// ---------------- transpose + convert ----------------
__global__ void transpose_cvt_kernel(const float* __restrict__ in, ushort_t* __restrict__ out,
                                     int rows, int cols) {
  __shared__ float tile[32][33];
  int tx = threadIdx.x & 31, ty = threadIdx.x >> 5;
  int r0 = blockIdx.y * 32, c0 = blockIdx.x * 32;
#pragma unroll
  for (int i = 0; i < 32; i += 8)
    tile[ty + i][tx] = in[(size_t)(r0 + ty + i) * cols + c0 + tx];
  __syncthreads();
#pragma unroll
  for (int i = 0; i < 32; i += 8)
    out[(size_t)(c0 + ty + i) * rows + r0 + tx] = f2b(tile[tx][ty + i]);
}

// ---------------- 256x256 8-phase QKV GEMM (T3+T4: counted vmcnt, never 0) ----
// BM=BN=256, BK=64, 8 waves (2M x 4N), quadrant-interleaved wave tiles:
// wave (wm,wn), quadrant (qm,qn) = rows qm*128+wm*64+[0,64), cols qn*128+wn*32+[0,32)
// -> phase (qm,qn) touches ONLY A-half qm + B-half qn. One half-tile staged per
// phase (2 gload_lds/thread); stage order p1:A(T+1)h1 p2:B(T+1)h1 p3:A(T+2)h0
// p4:B(T+2)h0 (regions dead >=1 phase before overwrite; consume lag >= 4 phases).
// vmcnt(4) + raw s_barrier at each phase top. LDS 128KB -> 1 block/CU.
// Epilogue: scatter-write q(*0.125*log2e)/k/vT bf16.
#define G256_PHASE(CUR, QM, QN)                                                     \
  {                                                                                 \
    short8 a[4][2], b[2][2];                                                        \
    _Pragma("unroll") for (int f = 0; f < 4; ++f)                                   \
        _Pragma("unroll") for (int kk = 0; kk < 2; ++kk) {                          \
      int row = (QM) * 128 + wm * 64 + f * 16 + lr;                                 \
      a[f][kk] = *(const short8*)(&lA[CUR][row * 64 + (((kk * 4 + lg) ^ (row & 7)) << 3)]); \
    }                                                                               \
    _Pragma("unroll") for (int g = 0; g < 2; ++g)                                   \
        _Pragma("unroll") for (int kk = 0; kk < 2; ++kk) {                          \
      int row = (QN) * 128 + wn * 32 + g * 16 + lr;                                 \
      b[g][kk] = *(const short8*)(&lB[CUR][row * 64 + (((kk * 4 + lg) ^ (row & 7)) << 3)]); \
    }                                                                               \
    __builtin_amdgcn_s_setprio(1);                                                  \
    _Pragma("unroll") for (int kk = 0; kk < 2; ++kk)                                \
        _Pragma("unroll") for (int f = 0; f < 4; ++f)                               \
            _Pragma("unroll") for (int g = 0; g < 2; ++g)                           \
                acc[QM][QN][f][g] = mfma_bf16(a[f][kk], b[g][kk], acc[QM][QN][f][g]); \
    __builtin_amdgcn_s_setprio(0);                                                  \
  }

#define G256_TOP()                                   \
  asm volatile("s_waitcnt vmcnt(4)" ::: "memory");   \
  __builtin_amdgcn_sched_barrier(0);                 \
  __builtin_amdgcn_s_barrier();                      \
  __builtin_amdgcn_sched_barrier(0);

__global__ __launch_bounds__(512, 1)
void gemm256_kernel(const ushort_t* __restrict__ A, const ushort_t* __restrict__ BT,
                    int M, int N, int K,
                    ushort_t* __restrict__ qg, ushort_t* __restrict__ kg,
                    ushort_t* __restrict__ vTg) {
  __shared__ ushort_t lA[2][256 * 64];  // 64KB: dbuf x (256 rows x 64 cols)
  __shared__ ushort_t lB[2][256 * 64];  // 64KB

  int tid = threadIdx.x;
  int lane = tid & 63, wv = tid >> 6;
  int wm = wv >> 2, wn = wv & 3;
  int lr = lane & 15, lg = lane >> 4;
  int m0 = blockIdx.x * 256, n0 = blockIdx.y * 256;
  int nt = K >> 6;

  const ushort_t* Ab = A + (size_t)m0 * K;
  const ushort_t* Bb = BT + (size_t)n0 * K;

  // stage half h of tile t for one matrix (2 x gload16/thread, linear LDS dest,
  // pre-swizzled global source)
  auto stageA = [&](int t, int h) {
    int k0 = t << 6;
#pragma unroll
    for (int ld = 0; ld < 2; ++ld) {
      int c = ld * 512 + tid;
      int row = c >> 3, cc = c & 7;
      gload16(Ab + (size_t)(h * 128 + row) * K + k0 + ((cc ^ (row & 7)) << 3),
              &lA[t & 1][(h * 128 + row) * 64 + cc * 8]);
    }
  };
  auto stageB = [&](int t, int h) {
    int k0 = t << 6;
#pragma unroll
    for (int ld = 0; ld < 2; ++ld) {
      int c = ld * 512 + tid;
      int row = c >> 3, cc = c & 7;
      gload16(Bb + (size_t)(h * 128 + row) * K + k0 + ((cc ^ (row & 7)) << 3),
              &lB[t & 1][(h * 128 + row) * 64 + cc * 8]);
    }
  };

  f32x4 acc[2][2][4][2];
  const f32x4 z4 = {0.f, 0.f, 0.f, 0.f};
#pragma unroll
  for (int qm = 0; qm < 2; ++qm)
#pragma unroll
    for (int qn = 0; qn < 2; ++qn)
#pragma unroll
      for (int f = 0; f < 4; ++f)
#pragma unroll
        for (int g = 0; g < 2; ++g) acc[qm][qn][f][g] = z4;

  // prologue: T0 all 4 halves + T1 h0 halves (issue order = vmcnt order)
  stageA(0, 0); stageB(0, 0);
  stageA(0, 1); stageB(0, 1);
  stageA(1, 0); stageB(1, 0);

  for (int T = 0; T < nt; ++T) {
    int cur = T & 1;
    G256_TOP();
    if (T + 1 < nt) stageA(T + 1, 1);
    G256_PHASE(cur, 0, 0);
    G256_TOP();
    if (T + 1 < nt) stageB(T + 1, 1);
    G256_PHASE(cur, 0, 1);
    G256_TOP();
    if (T + 2 < nt) stageA(T + 2, 0);
    G256_PHASE(cur, 1, 0);
    G256_TOP();
    if (T + 2 < nt) stageB(T + 2, 0);
    G256_PHASE(cur, 1, 1);
  }

  // epilogue: scatter q (*0.125*log2e) / k / vT
#pragma unroll
  for (int qm = 0; qm < 2; ++qm)
#pragma unroll
    for (int qn = 0; qn < 2; ++qn)
#pragma unroll
      for (int f = 0; f < 4; ++f)
#pragma unroll
        for (int g = 0; g < 2; ++g)
#pragma unroll
          for (int r = 0; r < 4; ++r) {
            int i = m0 + qm * 128 + wm * 64 + f * 16 + lg * 4 + r;
            int j = n0 + qn * 128 + wn * 32 + g * 16 + lr;
            int mat = j >> 10, rem = j & 1023;
            int h = rem >> 6, d = rem & 63;
            int b = i >> 12, s = i & 4095;
            int bh = b * HEADS + h;
            float v = acc[qm][qn][f][g][r];
            ushort_t val = f2b(mat == 0 ? v * 0.18033688f : v);
            if (mat == 0)      qg[((size_t)bh * SEQ + s) * DHEAD + d] = val;
            else if (mat == 1) kg[((size_t)bh * SEQ + s) * DHEAD + d] = val;
            else               vTg[((size_t)bh * DHEAD + d) * SEQ + s] = val;
          }
}

// ---------------- bf16 GEMM (128^2, R11/R13 proven form) for out-proj ----------
__global__ __launch_bounds__(256, 2)
void gemm_out_kernel(const ushort_t* __restrict__ A, const ushort_t* __restrict__ BT,
                     int M, int N, int K, float* __restrict__ outf) {
  __shared__ ushort_t lA[128 * 64];
  __shared__ ushort_t lB[128 * 64];
  int tid = threadIdx.x;
  int lane = tid & 63, w = tid >> 6;
  int m0 = blockIdx.x * 128, n0 = blockIdx.y * 128;
  int wr = (w >> 1) * 64, wc = (w & 1) * 64;
  int lr = lane & 15, lg = lane >> 4;

  const f32x4 z4 = {0.f, 0.f, 0.f, 0.f};
  f32x4 acc[4][4];
#pragma unroll
  for (int m = 0; m < 4; ++m)
#pragma unroll
    for (int n = 0; n < 4; ++n) acc[m][n] = z4;

  int ktiles = K >> 6;
  for (int kt = 0; kt < ktiles; ++kt) {
    int k0 = kt << 6;
#pragma unroll
    for (int i = 0; i < 4; ++i) {
      int c = i * 256 + tid;
      int row = c >> 3, cc = c & 7;
      gload16(A + (size_t)(m0 + row) * K + k0 + (cc ^ (row & 7)) * 8, lA + c * 8);
    }
#pragma unroll
    for (int i = 0; i < 4; ++i) {
      int c = i * 256 + tid;
      int row = c >> 3, cc = c & 7;
      gload16(BT + (size_t)(n0 + row) * K + k0 + (cc ^ (row & 7)) * 8, lB + c * 8);
    }
    __syncthreads();
#pragma unroll
    for (int kk = 0; kk < 2; ++kk) {
      short8 a[4], b[4];
#pragma unroll
      for (int m = 0; m < 4; ++m) {
        int row = wr + m * 16 + lr, cc = kk * 4 + lg;
        a[m] = *(const short8*)(lA + row * 64 + ((cc ^ (row & 7)) << 3));
      }
#pragma unroll
      for (int n = 0; n < 4; ++n) {
        int row = wc + n * 16 + lr, cc = kk * 4 + lg;
        b[n] = *(const short8*)(lB + row * 64 + ((cc ^ (row & 7)) << 3));
      }
      __builtin_amdgcn_s_setprio(1);
#pragma unroll
      for (int m = 0; m < 4; ++m)
#pragma unroll
        for (int n = 0; n < 4; ++n)
          acc[m][n] = mfma_bf16(a[m], b[n], acc[m][n]);
      __builtin_amdgcn_s_setprio(0);
    }
    __syncthreads();
  }

#pragma unroll
  for (int m = 0; m < 4; ++m)
#pragma unroll
    for (int n = 0; n < 4; ++n)
#pragma unroll
      for (int r = 0; r < 4; ++r) {
        int i = m0 + wr + m * 16 + lg * 4 + r;
        int j = n0 + wc + n * 16 + lr;
        outf[(size_t)i * N + j] = acc[m][n][r];
      }
}

// ---------------- flash attention (R13 proven: 112us) ----------------
struct QS {
  short8 qf[4];
  f32x16 o[2];
  f32x16 lacc;
  float mrow;
};

__device__ __forceinline__ void attn_qk_sm(int diag, int w, int l31, int hi, int lane,
                                           const ushort_t* lKc, QS& st, short8 (&pa)[8]) {
  f32x16 s[4];
#pragma unroll
  for (int t = 0; t < 4; ++t)
#pragma unroll
    for (int r = 0; r < 16; ++r) s[t][r] = 0.f;

#pragma unroll
  for (int t = 0; t < 4; ++t) {
    int row = t * 32 + l31;
#pragma unroll
    for (int kb = 0; kb < 4; ++kb) {
      int cc = kb * 2 + hi;
      short8 kf = *(const short8*)(lKc + row * 64 + ((cc ^ (row & 7)) << 3));
      __builtin_amdgcn_s_setprio(1);
      s[t] = mfma32_bf16(kf, st.qf[kb], s[t]);
      __builtin_amdgcn_s_setprio(0);
    }
  }

  if (diag) {
    int q = w * 32 + l31;
#pragma unroll
    for (int t = 0; t < 4; ++t)
#pragma unroll
      for (int r = 0; r < 16; ++r)
        if (t * 32 + (r & 3) + 8 * (r >> 2) + 4 * hi > q) s[t][r] = -1e30f;
  }

  float mx = fmaxf(s[0][0], s[0][1]);
#pragma unroll
  for (int t = 0; t < 4; ++t)
#pragma unroll
    for (int r = (t == 0 ? 2 : 0); r < 16; r += 2)
      mx = max3f(mx, s[t][r], s[t][r + 1]);
  mx = fmaxf(mx, __shfl_xor(mx, 32));
  float mo = st.mrow;
  if (!__all(mx - mo <= 8.0f)) {
    float mn = fmaxf(mo, mx);
    float al = exp2_fast(mo - mn);
    st.mrow = mn;
#pragma unroll
    for (int r = 0; r < 16; ++r) {
      float alo = __shfl(al, (r & 3) + 8 * (r >> 2) + 4 * hi);
      st.o[0][r] *= alo;
      st.o[1][r] *= alo;
      st.lacc[r] *= alo;
    }
  }
  float mloc = st.mrow;
#pragma unroll
  for (int t = 0; t < 4; ++t)
#pragma unroll
    for (int r = 0; r < 16; ++r)
      s[t][r] = exp2_fast(s[t][r] - mloc);

#pragma unroll
  for (int t = 0; t < 4; ++t) {
    uint_t w0 = cvt_pk_bf16(s[t][0], s[t][1]);
    uint_t w1 = cvt_pk_bf16(s[t][2], s[t][3]);
    uint_t w2 = cvt_pk_bf16(s[t][4], s[t][5]);
    uint_t w3 = cvt_pk_bf16(s[t][6], s[t][7]);
    permlane_swap(w0, w2);
    permlane_swap(w1, w3);
    u32x4 f0 = {w0, w1, w2, w3};
    pa[2 * t] = __builtin_bit_cast(short8, f0);
    uint_t w4 = cvt_pk_bf16(s[t][8], s[t][9]);
    uint_t w5 = cvt_pk_bf16(s[t][10], s[t][11]);
    uint_t w6 = cvt_pk_bf16(s[t][12], s[t][13]);
    uint_t w7 = cvt_pk_bf16(s[t][14], s[t][15]);
    permlane_swap(w4, w6);
    permlane_swap(w5, w7);
    u32x4 f1 = {w4, w5, w6, w7};
    pa[2 * t + 1] = __builtin_bit_cast(short8, f1);
  }
}

__device__ __forceinline__ void attn_pv(const ushort_t* lVc, int l31, int hi,
                                        const short8 (&pa)[8], const short8 ones8, QS& st) {
#pragma unroll
  for (int kb = 0; kb < 8; ++kb) {
    int cc = kb * 2 + hi;
    int row0 = l31, row1 = 32 + l31;
    short8 vf0 = *(const short8*)(lVc + row0 * 128 + ((cc ^ (row0 & 15)) << 3));
    short8 vf1 = *(const short8*)(lVc + row1 * 128 + ((cc ^ (row1 & 15)) << 3));
    __builtin_amdgcn_s_setprio(1);
    st.o[0] = mfma32_bf16(pa[kb], vf0, st.o[0]);
    st.lacc = mfma32_bf16(pa[kb], ones8, st.lacc);
    st.o[1] = mfma32_bf16(pa[kb], vf1, st.o[1]);
    __builtin_amdgcn_s_setprio(0);
  }
}

__device__ __forceinline__ void attn_epilogue(const QS& st, int q0, int bh,
                                              int w, int l31, int hi,
                                              ushort_t* __restrict__ og) {
  int b = bh >> 4, h = bh & 15;
#pragma unroll
  for (int r = 0; r < 16; ++r) {
    int qr = (r & 3) + 8 * (r >> 2) + 4 * hi;
    float inv = 1.0f / st.lacc[r];
    int srow = q0 + w * 32 + qr;
#pragma unroll
    for (int nd = 0; nd < 2; ++nd) {
      int col = h * 64 + nd * 32 + l31;
      og[((size_t)b * SEQ + srow) * HID + col] = f2b(st.o[nd][r] * inv);
    }
  }
}

__global__ __launch_bounds__(256, 2)
void attn_kernel(const ushort_t* __restrict__ qg, const ushort_t* __restrict__ kg,
                 const ushort_t* __restrict__ vTg, ushort_t* __restrict__ og) {
  __shared__ ushort_t lK[2][128 * 64];
  __shared__ ushort_t lV[64 * 128];

  int bid = blockIdx.x;
  int xcd = bid & 7, idx = bid >> 3;
  int bh = xcd * 4 + (idx & 3);
  int qt = 31 - (idx >> 2);
  int q0 = qt * 128;
  const ushort_t* Q = qg + (size_t)bh * SEQ * DHEAD;
  const ushort_t* Kp = kg + (size_t)bh * SEQ * DHEAD;
  const ushort_t* Vt = vTg + (size_t)bh * DHEAD * SEQ;

  int tid = threadIdx.x, lane = tid & 63, w = tid >> 6;
  int l31 = lane & 31, hi = lane >> 5;

  short8 ones8;
#pragma unroll
  for (int i = 0; i < 8; ++i) ones8[i] = (short)0x3F80;

#pragma unroll
  for (int i = 0; i < 4; ++i) {
    int c = i * 256 + tid;
    int row = c >> 3, cc = c & 7;
    size_t off = (cc ^ (row & 7)) * 8;
    gload16(Q + (size_t)(q0 + row) * DHEAD + off, &lV[c * 8]);
    gload16(Kp + (size_t)row * DHEAD + off, &lK[0][c * 8]);
  }
  __syncthreads();

  QS st;
  int qrow = w * 32 + l31;
#pragma unroll
  for (int kb = 0; kb < 4; ++kb) {
    int cc = kb * 2 + hi;
    st.qf[kb] = *(const short8*)(&lV[0] + qrow * 64 + ((cc ^ (qrow & 7)) << 3));
  }
  asm volatile("s_waitcnt lgkmcnt(0)");
  __syncthreads();

  st.mrow = -1e30f;
#pragma unroll
  for (int r = 0; r < 16; ++r) { st.o[0][r] = 0.f; st.o[1][r] = 0.f; st.lacc[r] = 0.f; }

  for (int jt = 0; jt <= qt; ++jt) {
    int cur = jt & 1, nxt = cur ^ 1;
#pragma unroll
    for (int i = 0; i < 4; ++i) {
      int c = i * 256 + tid;
      int d = c >> 4, cc = c & 15;
      gload16(Vt + (size_t)d * SEQ + jt * 128 + (cc ^ (d & 15)) * 8, &lV[c * 8]);
    }
    if (jt < qt) {
      int j0n = (jt + 1) * 128;
#pragma unroll
      for (int i = 0; i < 4; ++i) {
        int c = i * 256 + tid;
        int row = c >> 3, cc = c & 7;
        gload16(Kp + (size_t)(j0n + row) * DHEAD + (cc ^ (row & 7)) * 8, &lK[nxt][c * 8]);
      }
    }

    short8 pa[8];
    attn_qk_sm(jt == qt, w, l31, hi, lane, &lK[cur][0], st, pa);

    __syncthreads();
    attn_pv(&lV[0], l31, hi, pa, ones8, st);
    __syncthreads();
  }

  attn_epilogue(st, q0, bh, w, l31, hi, og);
}

extern "C" void kernel_launch(void* const* d_in, const int* in_sizes, int n_in,
                              void* d_out, int out_size, void* d_ws, size_t ws_size,
                              hipStream_t stream) {
  const float* x = (const float*)d_in[0];
  const float* wqkv = (const float*)d_in[1];
  const float* wout = (const float*)d_in[2];
  float* out = (float*)d_out;

  if (ws_size < 75497472u) return;  // need 75.5 MB scratch

  char* ws = (char*)d_ws;
  ushort_t* xb    = (ushort_t*)(ws);               // 8192x1024 bf16 (reused as attn out)
  ushort_t* wqkvT = (ushort_t*)(ws + 16777216);    // 3072x1024
  ushort_t* woutT = (ushort_t*)(ws + 23068672);    // 1024x1024
  ushort_t* qgb   = (ushort_t*)(ws + 25165824);    // [32][4096][64]
  ushort_t* kgb   = (ushort_t*)(ws + 41943040);    // [32][4096][64]
  ushort_t* vTb   = (ushort_t*)(ws + 58720256);    // [32][64][4096]
  ushort_t* ob    = xb;

  cvt_kernel<<<dim3(8192), dim3(256), 0, stream>>>(x, xb, 2097152);
  transpose_cvt_kernel<<<dim3(96, 32), dim3(256), 0, stream>>>(wqkv, wqkvT, 1024, 3072);
  transpose_cvt_kernel<<<dim3(32, 32), dim3(256), 0, stream>>>(wout, woutT, 1024, 1024);
  gemm256_kernel<<<dim3(32, 12), dim3(512), 0, stream>>>(xb, wqkvT, 8192, 3072, 1024,
                                                         qgb, kgb, vTb);
  attn_kernel<<<dim3(1024), dim3(256), 0, stream>>>(qgb, kgb, vTb, ob);
  gemm_out_kernel<<<dim3(64, 8), dim3(256), 0, stream>>>(ob, woutT, 8192, 1024, 1024, out);
}

// Round 15
// 234.811 us; speedup vs baseline: 1.0795x; 1.0795x over previous
//
#include <hip/hip_runtime.h>
#include <hip/hip_bf16.h>

#define SEQ 4096
#define BATCH 2
#define HEADS 16
#define DHEAD 64
#define HID 1024

typedef unsigned short ushort_t;
typedef unsigned int uint_t;
typedef __attribute__((ext_vector_type(8))) short short8;
typedef __attribute__((ext_vector_type(4))) float f32x4;
typedef __attribute__((ext_vector_type(16))) float f32x16;
typedef __attribute__((ext_vector_type(4))) uint_t u32x4;

__device__ __forceinline__ float exp2_fast(float x) {
  return __builtin_amdgcn_exp2f(x);
}

__device__ __forceinline__ float max3f(float a, float b, float c) {
  float r;
  asm("v_max3_f32 %0, %1, %2, %3" : "=v"(r) : "v"(a), "v"(b), "v"(c));
  return r;
}

__device__ __forceinline__ ushort_t f2b(float f) {
  unsigned u = __builtin_bit_cast(unsigned, f);
  unsigned r = 0x7fffu + ((u >> 16) & 1u);
  return (ushort_t)((u + r) >> 16);
}

__device__ __forceinline__ uint_t cvt_pk_bf16(float lo, float hi) {
  uint_t r;
  asm("v_cvt_pk_bf16_f32 %0, %1, %2" : "=v"(r) : "v"(lo), "v"(hi));
  return r;
}

__device__ __forceinline__ void permlane_swap(uint_t& a, uint_t& b) {
  asm("v_permlane32_swap_b32 %0, %1" : "+v"(a), "+v"(b));
}

__device__ __forceinline__ void gload16(const void* g, void* l) {
  __builtin_amdgcn_global_load_lds((const __attribute__((address_space(1))) void*)g,
                                   (__attribute__((address_space(3))) void*)l, 16, 0, 0);
}

__device__ __forceinline__ f32x4 mfma_bf16(short8 a, short8 b, f32x4 c) {
  return __builtin_amdgcn_mfma_f32_16x16x32_bf16(a, b, c, 0, 0, 0);
}

__device__ __forceinline__ f32x16 mfma32_bf16(short8 a, short8 b, f32x16 c) {
  return __builtin_amdgcn_mfma_f32_32x32x16_bf16(a, b, c, 0, 0, 0);
}

// ---------------- fp32 -> bf16 elementwise (vectorized) ----------------
__global__ void cvt_kernel(const float* __restrict__ in, ushort_t* __restrict__ out, int n4) {
  int i = blockIdx.x * blockDim.x + threadIdx.x;
  if (i >= n4) return;
  float4 v = reinterpret_cast<const float4*>(in)[i];
  ushort4 o;
  o.x = f2b(v.x); o.y = f2b(v.y); o.z = f2b(v.z); o.w = f2b(v.w);
  reinterpret_cast<ushort4*>(out)[i] = o;
}

// ---------------- transpose + convert ----------------
__global__ void transpose_cvt_kernel(const float* __restrict__ in, ushort_t* __restrict__ out,
                                     int rows, int cols) {
  __shared__ float tile[32][33];
  int tx = threadIdx.x & 31, ty = threadIdx.x >> 5;
  int r0 = blockIdx.y * 32, c0 = blockIdx.x * 32;
#pragma unroll
  for (int i = 0; i < 32; i += 8)
    tile[ty + i][tx] = in[(size_t)(r0 + ty + i) * cols + c0 + tx];
  __syncthreads();
#pragma unroll
  for (int i = 0; i < 32; i += 8)
    out[(size_t)(c0 + ty + i) * rows + r0 + tx] = f2b(tile[tx][ty + i]);
}

// ---------------- 256x256 8-phase QKV GEMM, template-exact rhythm ----------------
// Per phase: {ds_reads pre-barrier} {1 half-tile stage} -> s_barrier ->
// lgkmcnt(0)+sched_barrier(0) -> setprio1, 16 MFMA, setprio0 -> s_barrier.
// vmcnt(4) ONCE per K-tile (before the tile's final barrier): drains exactly
// tile T+1's four halves while keeping 2 stages in flight. A-fragments read
// once per qm, reused across both qn phases. LDS 128KB -> 1 block/CU.
#define LDA_Q(QM)                                                                   \
  _Pragma("unroll") for (int f = 0; f < 4; ++f)                                     \
      _Pragma("unroll") for (int kk = 0; kk < 2; ++kk) {                            \
    int row = (QM) * 128 + wm * 64 + f * 16 + lr;                                   \
    a[f][kk] = *(const short8*)(&lA[cur][row * 64 + (((kk * 4 + lg) ^ (row & 7)) << 3)]); \
  }
#define LDB_Q(QN)                                                                   \
  _Pragma("unroll") for (int g = 0; g < 2; ++g)                                     \
      _Pragma("unroll") for (int kk = 0; kk < 2; ++kk) {                            \
    int row = (QN) * 128 + wn * 32 + g * 16 + lr;                                   \
    b[g][kk] = *(const short8*)(&lB[cur][row * 64 + (((kk * 4 + lg) ^ (row & 7)) << 3)]); \
  }
#define MF_Q(QM, QN)                                                                \
  __builtin_amdgcn_s_setprio(1);                                                    \
  _Pragma("unroll") for (int kk = 0; kk < 2; ++kk)                                  \
      _Pragma("unroll") for (int f = 0; f < 4; ++f)                                 \
          _Pragma("unroll") for (int g = 0; g < 2; ++g)                             \
              acc[QM][QN][f][g] = mfma_bf16(a[f][kk], b[g][kk], acc[QM][QN][f][g]); \
  __builtin_amdgcn_s_setprio(0);
#define WAIT_LGKM()                            \
  asm volatile("s_waitcnt lgkmcnt(0)");        \
  __builtin_amdgcn_sched_barrier(0);

__global__ __launch_bounds__(512, 1)
void gemm256_kernel(const ushort_t* __restrict__ A, const ushort_t* __restrict__ BT,
                    int M, int N, int K,
                    ushort_t* __restrict__ qg, ushort_t* __restrict__ kg,
                    ushort_t* __restrict__ vTg) {
  __shared__ ushort_t lA[2][256 * 64];  // 64KB
  __shared__ ushort_t lB[2][256 * 64];  // 64KB

  int tid = threadIdx.x;
  int lane = tid & 63, wv = tid >> 6;
  int wm = wv >> 2, wn = wv & 3;
  int lr = lane & 15, lg = lane >> 4;
  int m0 = blockIdx.x * 256, n0 = blockIdx.y * 256;
  int nt = K >> 6;

  const ushort_t* Ab = A + (size_t)m0 * K;
  const ushort_t* Bb = BT + (size_t)n0 * K;

  auto stageA = [&](int t, int h) {
    int k0 = t << 6;
#pragma unroll
    for (int ld = 0; ld < 2; ++ld) {
      int c = ld * 512 + tid;
      int row = c >> 3, cc = c & 7;
      gload16(Ab + (size_t)(h * 128 + row) * K + k0 + ((cc ^ (row & 7)) << 3),
              &lA[t & 1][(h * 128 + row) * 64 + cc * 8]);
    }
  };
  auto stageB = [&](int t, int h) {
    int k0 = t << 6;
#pragma unroll
    for (int ld = 0; ld < 2; ++ld) {
      int c = ld * 512 + tid;
      int row = c >> 3, cc = c & 7;
      gload16(Bb + (size_t)(h * 128 + row) * K + k0 + ((cc ^ (row & 7)) << 3),
              &lB[t & 1][(h * 128 + row) * 64 + cc * 8]);
    }
  };

  f32x4 acc[2][2][4][2];
  const f32x4 z4 = {0.f, 0.f, 0.f, 0.f};
#pragma unroll
  for (int qm = 0; qm < 2; ++qm)
#pragma unroll
    for (int qn = 0; qn < 2; ++qn)
#pragma unroll
      for (int f = 0; f < 4; ++f)
#pragma unroll
        for (int g = 0; g < 2; ++g) acc[qm][qn][f][g] = z4;

  // prologue: T0 all 4 halves + T1 h0; drain T0, publish via barrier
  stageA(0, 0); stageB(0, 0);
  stageA(0, 1); stageB(0, 1);
  stageA(1, 0); stageB(1, 0);
  asm volatile("s_waitcnt vmcnt(4)");
  __builtin_amdgcn_sched_barrier(0);
  __builtin_amdgcn_s_barrier();

  for (int T = 0; T < nt; ++T) {
    const int cur = T & 1;
    short8 a[4][2], b[2][2];

    // phase 1 (qm0,qn0)
    LDA_Q(0); LDB_Q(0);
    if (T + 1 < nt) stageA(T + 1, 1);
    __builtin_amdgcn_s_barrier();
    WAIT_LGKM();
    MF_Q(0, 0);
    __builtin_amdgcn_s_barrier();

    // phase 2 (qm0,qn1): reuse a
    LDB_Q(1);
    if (T + 1 < nt) stageB(T + 1, 1);
    __builtin_amdgcn_s_barrier();
    WAIT_LGKM();
    MF_Q(0, 1);
    __builtin_amdgcn_s_barrier();

    // phase 3 (qm1,qn0)
    LDA_Q(1); LDB_Q(0);
    if (T + 2 < nt) stageA(T + 2, 0);
    __builtin_amdgcn_s_barrier();
    WAIT_LGKM();
    MF_Q(1, 0);
    __builtin_amdgcn_s_barrier();

    // phase 4 (qm1,qn1)
    LDB_Q(1);
    if (T + 2 < nt) stageB(T + 2, 0);
    __builtin_amdgcn_s_barrier();
    WAIT_LGKM();
    MF_Q(1, 1);
    asm volatile("s_waitcnt vmcnt(4)");  // once per K-tile; drains tile T+1's halves
    __builtin_amdgcn_s_barrier();        // publish all waves' drains before next reads
  }

  // epilogue: scatter q (*0.125*log2e) / k / vT
#pragma unroll
  for (int qm = 0; qm < 2; ++qm)
#pragma unroll
    for (int qn = 0; qn < 2; ++qn)
#pragma unroll
      for (int f = 0; f < 4; ++f)
#pragma unroll
        for (int g = 0; g < 2; ++g)
#pragma unroll
          for (int r = 0; r < 4; ++r) {
            int i = m0 + qm * 128 + wm * 64 + f * 16 + lg * 4 + r;
            int j = n0 + qn * 128 + wn * 32 + g * 16 + lr;
            int mat = j >> 10, rem = j & 1023;
            int h = rem >> 6, d = rem & 63;
            int b2 = i >> 12, s = i & 4095;
            int bh = b2 * HEADS + h;
            float v = acc[qm][qn][f][g][r];
            ushort_t val = f2b(mat == 0 ? v * 0.18033688f : v);
            if (mat == 0)      qg[((size_t)bh * SEQ + s) * DHEAD + d] = val;
            else if (mat == 1) kg[((size_t)bh * SEQ + s) * DHEAD + d] = val;
            else               vTg[((size_t)bh * DHEAD + d) * SEQ + s] = val;
          }
}

// ---------------- bf16 GEMM (128^2, proven) for out-proj ----------------
__global__ __launch_bounds__(256, 2)
void gemm_out_kernel(const ushort_t* __restrict__ A, const ushort_t* __restrict__ BT,
                     int M, int N, int K, float* __restrict__ outf) {
  __shared__ ushort_t lA[128 * 64];
  __shared__ ushort_t lB[128 * 64];
  int tid = threadIdx.x;
  int lane = tid & 63, w = tid >> 6;
  int m0 = blockIdx.x * 128, n0 = blockIdx.y * 128;
  int wr = (w >> 1) * 64, wc = (w & 1) * 64;
  int lr = lane & 15, lg = lane >> 4;

  const f32x4 z4 = {0.f, 0.f, 0.f, 0.f};
  f32x4 acc[4][4];
#pragma unroll
  for (int m = 0; m < 4; ++m)
#pragma unroll
    for (int n = 0; n < 4; ++n) acc[m][n] = z4;

  int ktiles = K >> 6;
  for (int kt = 0; kt < ktiles; ++kt) {
    int k0 = kt << 6;
#pragma unroll
    for (int i = 0; i < 4; ++i) {
      int c = i * 256 + tid;
      int row = c >> 3, cc = c & 7;
      gload16(A + (size_t)(m0 + row) * K + k0 + (cc ^ (row & 7)) * 8, lA + c * 8);
    }
#pragma unroll
    for (int i = 0; i < 4; ++i) {
      int c = i * 256 + tid;
      int row = c >> 3, cc = c & 7;
      gload16(BT + (size_t)(n0 + row) * K + k0 + (cc ^ (row & 7)) * 8, lB + c * 8);
    }
    __syncthreads();
#pragma unroll
    for (int kk = 0; kk < 2; ++kk) {
      short8 a[4], b[4];
#pragma unroll
      for (int m = 0; m < 4; ++m) {
        int row = wr + m * 16 + lr, cc = kk * 4 + lg;
        a[m] = *(const short8*)(lA + row * 64 + ((cc ^ (row & 7)) << 3));
      }
#pragma unroll
      for (int n = 0; n < 4; ++n) {
        int row = wc + n * 16 + lr, cc = kk * 4 + lg;
        b[n] = *(const short8*)(lB + row * 64 + ((cc ^ (row & 7)) << 3));
      }
      __builtin_amdgcn_s_setprio(1);
#pragma unroll
      for (int m = 0; m < 4; ++m)
#pragma unroll
        for (int n = 0; n < 4; ++n)
          acc[m][n] = mfma_bf16(a[m], b[n], acc[m][n]);
      __builtin_amdgcn_s_setprio(0);
    }
    __syncthreads();
  }

#pragma unroll
  for (int m = 0; m < 4; ++m)
#pragma unroll
    for (int n = 0; n < 4; ++n)
#pragma unroll
      for (int r = 0; r < 4; ++r) {
        int i = m0 + wr + m * 16 + lg * 4 + r;
        int j = n0 + wc + n * 16 + lr;
        outf[(size_t)i * N + j] = acc[m][n][r];
      }
}

// ---------------- flash attention (R13 proven: 112us) ----------------
struct QS {
  short8 qf[4];
  f32x16 o[2];
  f32x16 lacc;
  float mrow;
};

__device__ __forceinline__ void attn_qk_sm(int diag, int w, int l31, int hi, int lane,
                                           const ushort_t* lKc, QS& st, short8 (&pa)[8]) {
  f32x16 s[4];
#pragma unroll
  for (int t = 0; t < 4; ++t)
#pragma unroll
    for (int r = 0; r < 16; ++r) s[t][r] = 0.f;

#pragma unroll
  for (int t = 0; t < 4; ++t) {
    int row = t * 32 + l31;
#pragma unroll
    for (int kb = 0; kb < 4; ++kb) {
      int cc = kb * 2 + hi;
      short8 kf = *(const short8*)(lKc + row * 64 + ((cc ^ (row & 7)) << 3));
      __builtin_amdgcn_s_setprio(1);
      s[t] = mfma32_bf16(kf, st.qf[kb], s[t]);
      __builtin_amdgcn_s_setprio(0);
    }
  }

  if (diag) {
    int q = w * 32 + l31;
#pragma unroll
    for (int t = 0; t < 4; ++t)
#pragma unroll
      for (int r = 0; r < 16; ++r)
        if (t * 32 + (r & 3) + 8 * (r >> 2) + 4 * hi > q) s[t][r] = -1e30f;
  }

  float mx = fmaxf(s[0][0], s[0][1]);
#pragma unroll
  for (int t = 0; t < 4; ++t)
#pragma unroll
    for (int r = (t == 0 ? 2 : 0); r < 16; r += 2)
      mx = max3f(mx, s[t][r], s[t][r + 1]);
  mx = fmaxf(mx, __shfl_xor(mx, 32));
  float mo = st.mrow;
  if (!__all(mx - mo <= 8.0f)) {
    float mn = fmaxf(mo, mx);
    float al = exp2_fast(mo - mn);
    st.mrow = mn;
#pragma unroll
    for (int r = 0; r < 16; ++r) {
      float alo = __shfl(al, (r & 3) + 8 * (r >> 2) + 4 * hi);
      st.o[0][r] *= alo;
      st.o[1][r] *= alo;
      st.lacc[r] *= alo;
    }
  }
  float mloc = st.mrow;
#pragma unroll
  for (int t = 0; t < 4; ++t)
#pragma unroll
    for (int r = 0; r < 16; ++r)
      s[t][r] = exp2_fast(s[t][r] - mloc);

#pragma unroll
  for (int t = 0; t < 4; ++t) {
    uint_t w0 = cvt_pk_bf16(s[t][0], s[t][1]);
    uint_t w1 = cvt_pk_bf16(s[t][2], s[t][3]);
    uint_t w2 = cvt_pk_bf16(s[t][4], s[t][5]);
    uint_t w3 = cvt_pk_bf16(s[t][6], s[t][7]);
    permlane_swap(w0, w2);
    permlane_swap(w1, w3);
    u32x4 f0 = {w0, w1, w2, w3};
    pa[2 * t] = __builtin_bit_cast(short8, f0);
    uint_t w4 = cvt_pk_bf16(s[t][8], s[t][9]);
    uint_t w5 = cvt_pk_bf16(s[t][10], s[t][11]);
    uint_t w6 = cvt_pk_bf16(s[t][12], s[t][13]);
    uint_t w7 = cvt_pk_bf16(s[t][14], s[t][15]);
    permlane_swap(w4, w6);
    permlane_swap(w5, w7);
    u32x4 f1 = {w4, w5, w6, w7};
    pa[2 * t + 1] = __builtin_bit_cast(short8, f1);
  }
}

__device__ __forceinline__ void attn_pv(const ushort_t* lVc, int l31, int hi,
                                        const short8 (&pa)[8], const short8 ones8, QS& st) {
#pragma unroll
  for (int kb = 0; kb < 8; ++kb) {
    int cc = kb * 2 + hi;
    int row0 = l31, row1 = 32 + l31;
    short8 vf0 = *(const short8*)(lVc + row0 * 128 + ((cc ^ (row0 & 15)) << 3));
    short8 vf1 = *(const short8*)(lVc + row1 * 128 + ((cc ^ (row1 & 15)) << 3));
    __builtin_amdgcn_s_setprio(1);
    st.o[0] = mfma32_bf16(pa[kb], vf0, st.o[0]);
    st.lacc = mfma32_bf16(pa[kb], ones8, st.lacc);
    st.o[1] = mfma32_bf16(pa[kb], vf1, st.o[1]);
    __builtin_amdgcn_s_setprio(0);
  }
}

__device__ __forceinline__ void attn_epilogue(const QS& st, int q0, int bh,
                                              int w, int l31, int hi,
                                              ushort_t* __restrict__ og) {
  int b = bh >> 4, h = bh & 15;
#pragma unroll
  for (int r = 0; r < 16; ++r) {
    int qr = (r & 3) + 8 * (r >> 2) + 4 * hi;
    float inv = 1.0f / st.lacc[r];
    int srow = q0 + w * 32 + qr;
#pragma unroll
    for (int nd = 0; nd < 2; ++nd) {
      int col = h * 64 + nd * 32 + l31;
      og[((size_t)b * SEQ + srow) * HID + col] = f2b(st.o[nd][r] * inv);
    }
  }
}

__global__ __launch_bounds__(256, 2)
void attn_kernel(const ushort_t* __restrict__ qg, const ushort_t* __restrict__ kg,
                 const ushort_t* __restrict__ vTg, ushort_t* __restrict__ og) {
  __shared__ ushort_t lK[2][128 * 64];
  __shared__ ushort_t lV[64 * 128];

  int bid = blockIdx.x;
  int xcd = bid & 7, idx = bid >> 3;
  int bh = xcd * 4 + (idx & 3);
  int qt = 31 - (idx >> 2);
  int q0 = qt * 128;
  const ushort_t* Q = qg + (size_t)bh * SEQ * DHEAD;
  const ushort_t* Kp = kg + (size_t)bh * SEQ * DHEAD;
  const ushort_t* Vt = vTg + (size_t)bh * DHEAD * SEQ;

  int tid = threadIdx.x, lane = tid & 63, w = tid >> 6;
  int l31 = lane & 31, hi = lane >> 5;

  short8 ones8;
#pragma unroll
  for (int i = 0; i < 8; ++i) ones8[i] = (short)0x3F80;

#pragma unroll
  for (int i = 0; i < 4; ++i) {
    int c = i * 256 + tid;
    int row = c >> 3, cc = c & 7;
    size_t off = (cc ^ (row & 7)) * 8;
    gload16(Q + (size_t)(q0 + row) * DHEAD + off, &lV[c * 8]);
    gload16(Kp + (size_t)row * DHEAD + off, &lK[0][c * 8]);
  }
  __syncthreads();

  QS st;
  int qrow = w * 32 + l31;
#pragma unroll
  for (int kb = 0; kb < 4; ++kb) {
    int cc = kb * 2 + hi;
    st.qf[kb] = *(const short8*)(&lV[0] + qrow * 64 + ((cc ^ (qrow & 7)) << 3));
  }
  asm volatile("s_waitcnt lgkmcnt(0)");
  __syncthreads();

  st.mrow = -1e30f;
#pragma unroll
  for (int r = 0; r < 16; ++r) { st.o[0][r] = 0.f; st.o[1][r] = 0.f; st.lacc[r] = 0.f; }

  for (int jt = 0; jt <= qt; ++jt) {
    int cur = jt & 1, nxt = cur ^ 1;
#pragma unroll
    for (int i = 0; i < 4; ++i) {
      int c = i * 256 + tid;
      int d = c >> 4, cc = c & 15;
      gload16(Vt + (size_t)d * SEQ + jt * 128 + (cc ^ (d & 15)) * 8, &lV[c * 8]);
    }
    if (jt < qt) {
      int j0n = (jt + 1) * 128;
#pragma unroll
      for (int i = 0; i < 4; ++i) {
        int c = i * 256 + tid;
        int row = c >> 3, cc = c & 7;
        gload16(Kp + (size_t)(j0n + row) * DHEAD + (cc ^ (row & 7)) * 8, &lK[nxt][c * 8]);
      }
    }

    short8 pa[8];
    attn_qk_sm(jt == qt, w, l31, hi, lane, &lK[cur][0], st, pa);

    __syncthreads();
    attn_pv(&lV[0], l31, hi, pa, ones8, st);
    __syncthreads();
  }

  attn_epilogue(st, q0, bh, w, l31, hi, og);
}

extern "C" void kernel_launch(void* const* d_in, const int* in_sizes, int n_in,
                              void* d_out, int out_size, void* d_ws, size_t ws_size,
                              hipStream_t stream) {
  const float* x = (const float*)d_in[0];
  const float* wqkv = (const float*)d_in[1];
  const float* wout = (const float*)d_in[2];
  float* out = (float*)d_out;

  if (ws_size < 75497472u) return;  // need 75.5 MB scratch

  char* ws = (char*)d_ws;
  ushort_t* xb    = (ushort_t*)(ws);               // 8192x1024 bf16 (reused as attn out)
  ushort_t* wqkvT = (ushort_t*)(ws + 16777216);    // 3072x1024
  ushort_t* woutT = (ushort_t*)(ws + 23068672);    // 1024x1024
  ushort_t* qgb   = (ushort_t*)(ws + 25165824);    // [32][4096][64]
  ushort_t* kgb   = (ushort_t*)(ws + 41943040);    // [32][4096][64]
  ushort_t* vTb   = (ushort_t*)(ws + 58720256);    // [32][64][4096]
  ushort_t* ob    = xb;

  cvt_kernel<<<dim3(8192), dim3(256), 0, stream>>>(x, xb, 2097152);
  transpose_cvt_kernel<<<dim3(96, 32), dim3(256), 0, stream>>>(wqkv, wqkvT, 1024, 3072);
  transpose_cvt_kernel<<<dim3(32, 32), dim3(256), 0, stream>>>(wout, woutT, 1024, 1024);
  gemm256_kernel<<<dim3(32, 12), dim3(512), 0, stream>>>(xb, wqkvT, 8192, 3072, 1024,
                                                         qgb, kgb, vTb);
  attn_kernel<<<dim3(1024), dim3(256), 0, stream>>>(qgb, kgb, vTb, ob);
  gemm_out_kernel<<<dim3(64, 8), dim3(256), 0, stream>>>(ob, woutT, 8192, 1024, 1024, out);
}

// Round 16
// 218.499 us; speedup vs baseline: 1.1601x; 1.0747x over previous
//
#include <hip/hip_runtime.h>
#include <hip/hip_bf16.h>

#define SEQ 4096
#define BATCH 2
#define HEADS 16
#define DHEAD 64
#define HID 1024

typedef unsigned short ushort_t;
typedef unsigned int uint_t;
typedef __attribute__((ext_vector_type(8))) short short8;
typedef __attribute__((ext_vector_type(4))) float f32x4;
typedef __attribute__((ext_vector_type(16))) float f32x16;
typedef __attribute__((ext_vector_type(4))) uint_t u32x4;

__device__ __forceinline__ float exp2_fast(float x) {
  return __builtin_amdgcn_exp2f(x);  // v_exp_f32 computes 2^x natively
}

__device__ __forceinline__ float max3f(float a, float b, float c) {
  float r;
  asm("v_max3_f32 %0, %1, %2, %3" : "=v"(r) : "v"(a), "v"(b), "v"(c));
  return r;
}

__device__ __forceinline__ ushort_t f2b(float f) {
  unsigned u = __builtin_bit_cast(unsigned, f);
  unsigned r = 0x7fffu + ((u >> 16) & 1u);
  return (ushort_t)((u + r) >> 16);
}

__device__ __forceinline__ uint_t cvt_pk_bf16(float lo, float hi) {
  uint_t r;
  asm("v_cvt_pk_bf16_f32 %0, %1, %2" : "=v"(r) : "v"(lo), "v"(hi));
  return r;
}

// swap a's hi-32-lane half with b's lo-32-lane half (CDNA4 cross-lane, VALU pipe)
__device__ __forceinline__ void permlane_swap(uint_t& a, uint_t& b) {
  asm("v_permlane32_swap_b32 %0, %1" : "+v"(a), "+v"(b));
}

__device__ __forceinline__ void gload16(const void* g, void* l) {
  __builtin_amdgcn_global_load_lds((const __attribute__((address_space(1))) void*)g,
                                   (__attribute__((address_space(3))) void*)l, 16, 0, 0);
}

__device__ __forceinline__ f32x4 mfma_bf16(short8 a, short8 b, f32x4 c) {
  return __builtin_amdgcn_mfma_f32_16x16x32_bf16(a, b, c, 0, 0, 0);
}

__device__ __forceinline__ f32x16 mfma32_bf16(short8 a, short8 b, f32x16 c) {
  return __builtin_amdgcn_mfma_f32_32x32x16_bf16(a, b, c, 0, 0, 0);
}

// ---------------- fp32 -> bf16 elementwise (vectorized) ----------------
__global__ void cvt_kernel(const float* __restrict__ in, ushort_t* __restrict__ out, int n4) {
  int i = blockIdx.x * blockDim.x + threadIdx.x;
  if (i >= n4) return;
  float4 v = reinterpret_cast<const float4*>(in)[i];
  ushort4 o;
  o.x = f2b(v.x); o.y = f2b(v.y); o.z = f2b(v.z); o.w = f2b(v.w);
  reinterpret_cast<ushort4*>(out)[i] = o;
}

// ---------------- transpose + convert: in[rows][cols] f32 -> out[cols][rows] bf16 ----------------
__global__ void transpose_cvt_kernel(const float* __restrict__ in, ushort_t* __restrict__ out,
                                     int rows, int cols) {
  __shared__ float tile[32][33];
  int tx = threadIdx.x & 31, ty = threadIdx.x >> 5;
  int r0 = blockIdx.y * 32, c0 = blockIdx.x * 32;
#pragma unroll
  for (int i = 0; i < 32; i += 8)
    tile[ty + i][tx] = in[(size_t)(r0 + ty + i) * cols + c0 + tx];
  __syncthreads();
#pragma unroll
  for (int i = 0; i < 32; i += 8)
    out[(size_t)(c0 + ty + i) * rows + r0 + tx] = f2b(tile[tx][ty + i]);
}

// ---------------- bf16 GEMM: C = A[M][K] * BT[N][K]^T (proven 128^2 form) ----------------
// MODE 0: scatter-write q(*0.125*log2e)/k/vT bf16.  MODE 1: write fp32 C.
template <int MODE>
__global__ __launch_bounds__(256, 2)
void gemm_kernel(const ushort_t* __restrict__ A, const ushort_t* __restrict__ BT,
                 int M, int N, int K,
                 ushort_t* __restrict__ qg, ushort_t* __restrict__ kg,
                 ushort_t* __restrict__ vTg, float* __restrict__ outf) {
  __shared__ ushort_t lA[128 * 64];
  __shared__ ushort_t lB[128 * 64];
  int tid = threadIdx.x;
  int lane = tid & 63, w = tid >> 6;
  int m0 = blockIdx.x * 128, n0 = blockIdx.y * 128;
  int wr = (w >> 1) * 64, wc = (w & 1) * 64;
  int lr = lane & 15, lg = lane >> 4;

  const f32x4 z4 = {0.f, 0.f, 0.f, 0.f};
  f32x4 acc[4][4];
#pragma unroll
  for (int m = 0; m < 4; ++m)
#pragma unroll
    for (int n = 0; n < 4; ++n) acc[m][n] = z4;

  int ktiles = K >> 6;
  for (int kt = 0; kt < ktiles; ++kt) {
    int k0 = kt << 6;
#pragma unroll
    for (int i = 0; i < 4; ++i) {
      int c = i * 256 + tid;
      int row = c >> 3, cc = c & 7;
      gload16(A + (size_t)(m0 + row) * K + k0 + (cc ^ (row & 7)) * 8, lA + c * 8);
    }
#pragma unroll
    for (int i = 0; i < 4; ++i) {
      int c = i * 256 + tid;
      int row = c >> 3, cc = c & 7;
      gload16(BT + (size_t)(n0 + row) * K + k0 + (cc ^ (row & 7)) * 8, lB + c * 8);
    }
    __syncthreads();
#pragma unroll
    for (int kk = 0; kk < 2; ++kk) {
      short8 a[4], b[4];
#pragma unroll
      for (int m = 0; m < 4; ++m) {
        int row = wr + m * 16 + lr, cc = kk * 4 + lg;
        a[m] = *(const short8*)(lA + row * 64 + ((cc ^ (row & 7)) << 3));
      }
#pragma unroll
      for (int n = 0; n < 4; ++n) {
        int row = wc + n * 16 + lr, cc = kk * 4 + lg;
        b[n] = *(const short8*)(lB + row * 64 + ((cc ^ (row & 7)) << 3));
      }
      __builtin_amdgcn_s_setprio(1);
#pragma unroll
      for (int m = 0; m < 4; ++m)
#pragma unroll
        for (int n = 0; n < 4; ++n)
          acc[m][n] = mfma_bf16(a[m], b[n], acc[m][n]);
      __builtin_amdgcn_s_setprio(0);
    }
    __syncthreads();
  }

#pragma unroll
  for (int m = 0; m < 4; ++m)
#pragma unroll
    for (int n = 0; n < 4; ++n)
#pragma unroll
      for (int r = 0; r < 4; ++r) {
        int i = m0 + wr + m * 16 + lg * 4 + r;
        int j = n0 + wc + n * 16 + lr;
        float v = acc[m][n][r];
        if (MODE == 0) {
          int mat = j >> 10, rem = j & 1023;
          int h = rem >> 6, d = rem & 63;
          int b = i >> 12, s = i & 4095;
          int bh = b * HEADS + h;
          // fold 1/sqrt(64) * log2(e) into Q (softmax runs in exp2 domain)
          ushort_t val = f2b(mat == 0 ? v * 0.18033688f : v);
          if (mat == 0)      qg[((size_t)bh * SEQ + s) * DHEAD + d] = val;
          else if (mat == 1) kg[((size_t)bh * SEQ + s) * DHEAD + d] = val;
          else               vTg[((size_t)bh * DHEAD + d) * SEQ + s] = val;
        } else {
          outf[(size_t)i * N + j] = v;
        }
      }
}

// ---------------- flash attention, 32x32 MFMA + in-register P + MFMA row-sum ----------------
// One block per (bh, q-tile); grid 1024, XCD-pinned bh, heavy q-tiles first.
// LDS: lK dbuf 32KB + lV single 16KB = 48KB. Per iter: issue V(jt)+K(jt+1) ->
// QK+softmax (hides V latency) -> barrier -> PV -> barrier. P in registers
// (cvt_pk + permlane32_swap). Softmax denominator l = P*1 on the MATRIX pipe
// (ones-operand mfma into lacc, o-register layout).
struct QS {
  short8 qf[4];
  f32x16 o[2];
  f32x16 lacc;
  float mrow;
};

__device__ __forceinline__ void attn_qk_sm(int diag, int w, int l31, int hi, int lane,
                                           const ushort_t* lKc, QS& st, short8 (&pa)[8]) {
  f32x16 s[4];
#pragma unroll
  for (int t = 0; t < 4; ++t)
#pragma unroll
    for (int r = 0; r < 16; ++r) s[t][r] = 0.f;

#pragma unroll
  for (int t = 0; t < 4; ++t) {
    int row = t * 32 + l31;
#pragma unroll
    for (int kb = 0; kb < 4; ++kb) {
      int cc = kb * 2 + hi;
      short8 kf = *(const short8*)(lKc + row * 64 + ((cc ^ (row & 7)) << 3));
      __builtin_amdgcn_s_setprio(1);
      s[t] = mfma32_bf16(kf, st.qf[kb], s[t]);
      __builtin_amdgcn_s_setprio(0);
    }
  }

  if (diag) {
    int q = w * 32 + l31;
#pragma unroll
    for (int t = 0; t < 4; ++t)
#pragma unroll
      for (int r = 0; r < 16; ++r)
        if (t * 32 + (r & 3) + 8 * (r >> 2) + 4 * hi > q) s[t][r] = -1e30f;
  }

  float mx = fmaxf(s[0][0], s[0][1]);
#pragma unroll
  for (int t = 0; t < 4; ++t)
#pragma unroll
    for (int r = (t == 0 ? 2 : 0); r < 16; r += 2)
      mx = max3f(mx, s[t][r], s[t][r + 1]);
  mx = fmaxf(mx, __shfl_xor(mx, 32));
  float mo = st.mrow;
  if (!__all(mx - mo <= 8.0f)) {
    float mn = fmaxf(mo, mx);
    float al = exp2_fast(mo - mn);
    st.mrow = mn;
#pragma unroll
    for (int r = 0; r < 16; ++r) {
      float alo = __shfl(al, (r & 3) + 8 * (r >> 2) + 4 * hi);
      st.o[0][r] *= alo;
      st.o[1][r] *= alo;
      st.lacc[r] *= alo;
    }
  }
  float mloc = st.mrow;
#pragma unroll
  for (int t = 0; t < 4; ++t)
#pragma unroll
    for (int r = 0; r < 16; ++r)
      s[t][r] = exp2_fast(s[t][r] - mloc);

#pragma unroll
  for (int t = 0; t < 4; ++t) {
    uint_t w0 = cvt_pk_bf16(s[t][0], s[t][1]);
    uint_t w1 = cvt_pk_bf16(s[t][2], s[t][3]);
    uint_t w2 = cvt_pk_bf16(s[t][4], s[t][5]);
    uint_t w3 = cvt_pk_bf16(s[t][6], s[t][7]);
    permlane_swap(w0, w2);
    permlane_swap(w1, w3);
    u32x4 f0 = {w0, w1, w2, w3};
    pa[2 * t] = __builtin_bit_cast(short8, f0);
    uint_t w4 = cvt_pk_bf16(s[t][8], s[t][9]);
    uint_t w5 = cvt_pk_bf16(s[t][10], s[t][11]);
    uint_t w6 = cvt_pk_bf16(s[t][12], s[t][13]);
    uint_t w7 = cvt_pk_bf16(s[t][14], s[t][15]);
    permlane_swap(w4, w6);
    permlane_swap(w5, w7);
    u32x4 f1 = {w4, w5, w6, w7};
    pa[2 * t + 1] = __builtin_bit_cast(short8, f1);
  }
}

__device__ __forceinline__ void attn_pv(const ushort_t* lVc, int l31, int hi,
                                        const short8 (&pa)[8], const short8 ones8, QS& st) {
#pragma unroll
  for (int kb = 0; kb < 8; ++kb) {
    int cc = kb * 2 + hi;
    int row0 = l31, row1 = 32 + l31;
    short8 vf0 = *(const short8*)(lVc + row0 * 128 + ((cc ^ (row0 & 15)) << 3));
    short8 vf1 = *(const short8*)(lVc + row1 * 128 + ((cc ^ (row1 & 15)) << 3));
    __builtin_amdgcn_s_setprio(1);
    st.o[0] = mfma32_bf16(pa[kb], vf0, st.o[0]);
    st.lacc = mfma32_bf16(pa[kb], ones8, st.lacc);
    st.o[1] = mfma32_bf16(pa[kb], vf1, st.o[1]);
    __builtin_amdgcn_s_setprio(0);
  }
}

__device__ __forceinline__ void attn_epilogue(const QS& st, int q0, int bh,
                                              int w, int l31, int hi,
                                              ushort_t* __restrict__ og) {
  int b = bh >> 4, h = bh & 15;
#pragma unroll
  for (int r = 0; r < 16; ++r) {
    int qr = (r & 3) + 8 * (r >> 2) + 4 * hi;
    float inv = 1.0f / st.lacc[r];
    int srow = q0 + w * 32 + qr;
#pragma unroll
    for (int nd = 0; nd < 2; ++nd) {
      int col = h * 64 + nd * 32 + l31;
      og[((size_t)b * SEQ + srow) * HID + col] = f2b(st.o[nd][r] * inv);
    }
  }
}

__global__ __launch_bounds__(256, 2)
void attn_kernel(const ushort_t* __restrict__ qg, const ushort_t* __restrict__ kg,
                 const ushort_t* __restrict__ vTg, ushort_t* __restrict__ og) {
  __shared__ ushort_t lK[2][128 * 64];
  __shared__ ushort_t lV[64 * 128];

  int bid = blockIdx.x;
  int xcd = bid & 7, idx = bid >> 3;
  int bh = xcd * 4 + (idx & 3);
  int qt = 31 - (idx >> 2);
  int q0 = qt * 128;
  const ushort_t* Q = qg + (size_t)bh * SEQ * DHEAD;
  const ushort_t* Kp = kg + (size_t)bh * SEQ * DHEAD;
  const ushort_t* Vt = vTg + (size_t)bh * DHEAD * SEQ;

  int tid = threadIdx.x, lane = tid & 63, w = tid >> 6;
  int l31 = lane & 31, hi = lane >> 5;

  short8 ones8;
#pragma unroll
  for (int i = 0; i < 8; ++i) ones8[i] = (short)0x3F80;  // bf16 1.0

#pragma unroll
  for (int i = 0; i < 4; ++i) {
    int c = i * 256 + tid;
    int row = c >> 3, cc = c & 7;
    size_t off = (cc ^ (row & 7)) * 8;
    gload16(Q + (size_t)(q0 + row) * DHEAD + off, &lV[c * 8]);
    gload16(Kp + (size_t)row * DHEAD + off, &lK[0][c * 8]);
  }
  __syncthreads();

  QS st;
  int qrow = w * 32 + l31;
#pragma unroll
  for (int kb = 0; kb < 4; ++kb) {
    int cc = kb * 2 + hi;
    st.qf[kb] = *(const short8*)(&lV[0] + qrow * 64 + ((cc ^ (qrow & 7)) << 3));
  }
  asm volatile("s_waitcnt lgkmcnt(0)");
  __syncthreads();

  st.mrow = -1e30f;
#pragma unroll
  for (int r = 0; r < 16; ++r) { st.o[0][r] = 0.f; st.o[1][r] = 0.f; st.lacc[r] = 0.f; }

  for (int jt = 0; jt <= qt; ++jt) {
    int cur = jt & 1, nxt = cur ^ 1;
#pragma unroll
    for (int i = 0; i < 4; ++i) {
      int c = i * 256 + tid;
      int d = c >> 4, cc = c & 15;
      gload16(Vt + (size_t)d * SEQ + jt * 128 + (cc ^ (d & 15)) * 8, &lV[c * 8]);
    }
    if (jt < qt) {
      int j0n = (jt + 1) * 128;
#pragma unroll
      for (int i = 0; i < 4; ++i) {
        int c = i * 256 + tid;
        int row = c >> 3, cc = c & 7;
        gload16(Kp + (size_t)(j0n + row) * DHEAD + (cc ^ (row & 7)) * 8, &lK[nxt][c * 8]);
      }
    }

    short8 pa[8];
    attn_qk_sm(jt == qt, w, l31, hi, lane, &lK[cur][0], st, pa);

    __syncthreads();
    attn_pv(&lV[0], l31, hi, pa, ones8, st);
    __syncthreads();
  }

  attn_epilogue(st, q0, bh, w, l31, hi, og);
}

extern "C" void kernel_launch(void* const* d_in, const int* in_sizes, int n_in,
                              void* d_out, int out_size, void* d_ws, size_t ws_size,
                              hipStream_t stream) {
  const float* x = (const float*)d_in[0];
  const float* wqkv = (const float*)d_in[1];
  const float* wout = (const float*)d_in[2];
  float* out = (float*)d_out;

  if (ws_size < 75497472u) return;  // need 75.5 MB scratch

  char* ws = (char*)d_ws;
  ushort_t* xb    = (ushort_t*)(ws);               // 8192x1024 bf16 (reused as attn out)
  ushort_t* wqkvT = (ushort_t*)(ws + 16777216);    // 3072x1024
  ushort_t* woutT = (ushort_t*)(ws + 23068672);    // 1024x1024
  ushort_t* qgb   = (ushort_t*)(ws + 25165824);    // [32][4096][64]
  ushort_t* kgb   = (ushort_t*)(ws + 41943040);    // [32][4096][64]
  ushort_t* vTb   = (ushort_t*)(ws + 58720256);    // [32][64][4096]
  ushort_t* ob    = xb;

  cvt_kernel<<<dim3(8192), dim3(256), 0, stream>>>(x, xb, 2097152);
  transpose_cvt_kernel<<<dim3(96, 32), dim3(256), 0, stream>>>(wqkv, wqkvT, 1024, 3072);
  transpose_cvt_kernel<<<dim3(32, 32), dim3(256), 0, stream>>>(wout, woutT, 1024, 1024);
  gemm_kernel<0><<<dim3(64, 24), dim3(256), 0, stream>>>(xb, wqkvT, 8192, 3072, 1024,
                                                         qgb, kgb, vTb, nullptr);
  attn_kernel<<<dim3(1024), dim3(256), 0, stream>>>(qgb, kgb, vTb, ob);
  gemm_kernel<1><<<dim3(64, 8), dim3(256), 0, stream>>>(ob, woutT, 8192, 1024, 1024,
                                                        nullptr, nullptr, nullptr, out);
}